// Round 9
// baseline (1133.835 us; speedup 1.0000x reference)
//
#include <hip/hip_runtime.h>

// CRF log-likelihood: B=256, S=2048, L=64, START=62, END=63.
// One wave per batch element; lane i owns state i. Probability domain:
//   E_{s+1}[i] = l_s[i] * sum_j P[i][j] * E_s[j],  P = exp(T), l = exp(logit).
//
// P in LDS (packed f16 pairs, padded stride 36 -> conflict-free b128), loaded
// into q[8] registers once per 8-step block (amdgpu_waves_per_eu(1,1) lifts
// the RA budget so q stays resident — round-8: VGPR 132, -104 cyc/step).
//
// Round-9 changes (stall hunt — ~200 cyc/step unexplained in round 8):
//  (a) ALL 32 v_readlane broadcasts hoisted into one block before ALL 32
//      v_dot2 (SGPR-write->VALU-read hazard amortized across the block;
//      sched_barrier pins the boundary so the scheduler can't re-sink them).
//  (b) logits prefetch deepened 8 -> 16: even conservative vmcnt leaves >=8
//      loads in flight, so HBM/L3 latency can't leak into the step loop.
//
// Renorm per step by PROXY: exponent of f32 Ey at lane 0 (one v_readlane).
// Centered at 2^-10; exact power-of-2 bookkeeping in integer D.

#define Bsz 256
#define Ssz 2048
#define START_ 62
#define END_ 63
#define PSTRIDE 36   // dwords per LDS row: 32 data + 4 pad (conflict-free b128)

typedef __attribute__((ext_vector_type(2))) _Float16 half2v;

__device__ __forceinline__ unsigned pack_pkrtz(float a, float b) {
    auto h = __builtin_amdgcn_cvt_pkrtz(a, b);   // __fp16 ext_vector(2)
    return __builtin_bit_cast(unsigned, h);
}

__device__ __forceinline__ float dot2h(unsigned a, unsigned b, float c) {
#if __has_builtin(__builtin_amdgcn_fdot2)
    return __builtin_amdgcn_fdot2(__builtin_bit_cast(half2v, a),
                                  __builtin_bit_cast(half2v, b), c, false);
#else
    half2v ha = __builtin_bit_cast(half2v, a);
    half2v hb = __builtin_bit_cast(half2v, b);
    c = __builtin_fmaf((float)ha.x, (float)hb.x, c);
    return __builtin_fmaf((float)ha.y, (float)hb.y, c);
#endif
}

__device__ __forceinline__ float wave_sum(float v) {
#pragma unroll
    for (int m = 32; m >= 1; m >>= 1) v += __shfl_xor(v, m, 64);
    return v;
}

// One recurrence step; q[0..7] (this lane's P row, packed f16 pairs) must be
// in scope. LG = raw logit loaded 16 steps ago. Updates E (renormed
// prob-domain alpha, f32) and D (exact log2 of removed scale).
#define CRF_STEP(LG)                                                           \
    {                                                                          \
        const float l_ = __builtin_amdgcn_exp2f((LG) * L2E);                   \
        const int nbi_ = __builtin_amdgcn_update_dpp(                          \
            0, __float_as_int(E), 0xB1, 0xf, 0xf, true); /* quad_perm 1,0,3,2*/\
        const unsigned packed_ = pack_pkrtz(E, __int_as_float(nbi_));          \
        /* (a) all 32 broadcasts first — independent, pipeline back-to-back */ \
        unsigned t_[32];                                                       \
        _Pragma("unroll")                                                      \
        for (int k = 0; k < 32; ++k)                                           \
            t_[k] = (unsigned)__builtin_amdgcn_readlane((int)packed_, 2 * k);  \
        __builtin_amdgcn_sched_barrier(0);  /* don't re-sink readlanes */      \
        float c0 = 0.f, c1 = 0.f, c2 = 0.f, c3 = 0.f;                          \
        float c4 = 0.f, c5 = 0.f, c6 = 0.f, c7 = 0.f;                          \
        _Pragma("unroll")                                                      \
        for (int k8 = 0; k8 < 8; ++k8) {                                       \
            const uint4 q_ = q[k8];                                            \
            if (k8 & 1) {                                                      \
                c4 = dot2h(t_[4 * k8 + 0], q_.x, c4);                          \
                c5 = dot2h(t_[4 * k8 + 1], q_.y, c5);                          \
                c6 = dot2h(t_[4 * k8 + 2], q_.z, c6);                          \
                c7 = dot2h(t_[4 * k8 + 3], q_.w, c7);                          \
            } else {                                                           \
                c0 = dot2h(t_[4 * k8 + 0], q_.x, c0);                          \
                c1 = dot2h(t_[4 * k8 + 1], q_.y, c1);                          \
                c2 = dot2h(t_[4 * k8 + 2], q_.z, c2);                          \
                c3 = dot2h(t_[4 * k8 + 3], q_.w, c3);                          \
            }                                                                  \
        }                                                                      \
        const float y_ = ((c0 + c1) + (c2 + c3)) + ((c4 + c5) + (c6 + c7));    \
        const float Ey_ = y_ * l_;                                             \
        const int pb_ = __builtin_amdgcn_readlane(__float_as_int(Ey_), 0);     \
        const int ee_ = (pb_ >> 23) & 0xff;   /* proxy biased exponent */      \
        const float sc_ = __int_as_float((244 - ee_) << 23); /* 2^(117-ee) */  \
        E = Ey_ * sc_;                                                         \
        D += ee_ - 117;                                                        \
    }

// Reload this lane's P row from LDS into q[8] through an opaque address
// (fresh per call -> loads cannot be hoisted/CSE'd/remat'd across blocks).
#define LOAD_QBLOCK()                                                          \
    {                                                                          \
        unsigned off_ = (unsigned)(lane * (PSTRIDE * 4));                      \
        asm volatile("" : "+v"(off_));                                         \
        const uint4* prow_ = (const uint4*)((const char*)Psh + off_);          \
        _Pragma("unroll")                                                      \
        for (int k8 = 0; k8 < 8; ++k8) q[k8] = prow_[k8];                      \
    }

__global__ __launch_bounds__(64)
__attribute__((amdgpu_waves_per_eu(1, 1)))
void crf_kernel(const float* __restrict__ logits,
                const float* __restrict__ transition,
                const int* __restrict__ labels,
                const int* __restrict__ lens,
                float* __restrict__ out)
{
    const int b    = blockIdx.x;
    const int lane = threadIdx.x;
    const float L2E = 1.4426950408889634f;
    const float LN2 = 0.6931471805599453f;

    __shared__ unsigned Psh[64 * PSTRIDE];

    const int len = lens[b];                       // 1..2048, wave-uniform
    const float* lrow = logits + (size_t)b * (Ssz * 64);

    // Stage P[lane][j] = exp(T[lane][j]) as packed f16 pairs into LDS.
    // One-time; no barrier needed (single wave).
#pragma unroll
    for (int k = 0; k < 32; ++k) {
        float p0 = __builtin_amdgcn_exp2f(transition[lane * 64 + 2 * k]     * L2E);
        float p1 = __builtin_amdgcn_exp2f(transition[lane * 64 + 2 * k + 1] * L2E);
        Psh[lane * PSTRIDE + k] = pack_pkrtz(p0, p1);
    }
    asm volatile("s_waitcnt lgkmcnt(0)" ::: "memory");

    float E = (lane == START_) ? 1.0f : 0.0f;      // prob-domain alpha (renormed)
    int   D = 0;                                   // exact log2 of removed scale

    // (b) 16-deep rolling raw-logit prefetch (coalesced 256 B/row).
    float lgb[16];
#pragma unroll
    for (int d = 0; d < 16; ++d) {
        int s0 = (d < len) ? d : (len - 1);
        lgb[d] = lrow[s0 * 64 + lane];
    }

    uint4 q[8];
    const int len8 = len & ~7;
    for (int s = 0; s < len8; s += 8) {
        LOAD_QBLOCK();                             // 8x ds_read_b128 per 8 steps
#pragma unroll
        for (int d = 0; d < 8; ++d) {
            const int  si = s + d;
            const float lg = lgb[si & 15];
            int pf = si + 16;
            pf = (pf < len) ? pf : (len - 1);
            lgb[si & 15] = lrow[pf * 64 + lane];   // prefetch 16 ahead
            CRF_STEP(lg);
        }
    }
    const int rem = len - len8;
    if (rem) {
        LOAD_QBLOCK();
        for (int d = 0; d < rem; ++d) {            // <=7 iterations
            const float lg = lgb[(len8 + d) & 15];
            CRF_STEP(lg);
        }
    }

    // norm = ln2 * (D + log2(sum_i E_i * exp(T[END,i])))
    const float Pend = __builtin_amdgcn_exp2f(transition[END_ * 64 + lane] * L2E);
    const float tot  = wave_sum(E * Pend);
    const float norm = LN2 * ((float)D + __builtin_amdgcn_logf(tot));

    // Gold path score (exact).
    const int* lab = labels + (size_t)b * Ssz;
    float g = 0.0f;
    for (int s = lane; s < len; s += 64) {
        const int l1 = lab[s];
        const int l0 = (s == 0) ? START_ : lab[s - 1];
        g += lrow[s * 64 + l1] + transition[l1 * 64 + l0];
    }
    if (lane == 0) g += transition[END_ * 64 + lab[len - 1]];
    const float gold = wave_sum(g);

    if (lane == 0) out[b] = gold - norm;
}

extern "C" void kernel_launch(void* const* d_in, const int* in_sizes, int n_in,
                              void* d_out, int out_size, void* d_ws, size_t ws_size,
                              hipStream_t stream) {
    const float* logits     = (const float*)d_in[0];
    const float* transition = (const float*)d_in[1];
    const int*   labels     = (const int*)d_in[2];
    const int*   lens       = (const int*)d_in[3];
    float*       out        = (float*)d_out;

    crf_kernel<<<dim3(Bsz), dim3(64), 0, stream>>>(
        logits, transition, labels, lens, out);
}